// Round 16
// baseline (98.407 us; speedup 1.0000x reference)
//
#include <hip/hip_runtime.h>

// CrossAttention B=2, L=2048, E=1024, H=16, D=64
// cvt_all(+scan) -> gather -> QKV gemm (4-wave acc[4][4], XCD-swizzled, early-exit)
// -> attn (32x32 swapped MFMA, LDS dbuf, 4-wave KV-split, unnormalized softmax,
// lb folded into smem, tail-only mask loads) -> O gemm (8-wave, f32 out)

typedef unsigned short u16;
typedef unsigned int u32;
typedef __attribute__((ext_vector_type(2))) float f32x2;
typedef __attribute__((ext_vector_type(4))) float f32x4;
typedef __attribute__((ext_vector_type(16))) float f32x16;
typedef __attribute__((ext_vector_type(8))) short s16x8;
typedef __attribute__((ext_vector_type(4))) u16 u16x4;
typedef __attribute__((ext_vector_type(4))) u32 u32x4;

#define C_SCALE 0.18033688011112042f  // 0.125 * log2(e)
#define NEGBIG -30000.0f

__device__ __forceinline__ u16 f2bf(float f) {
  u32 u = __builtin_bit_cast(u32, f);
  u += 0x7FFFu + ((u >> 16) & 1u);
  return (u16)(u >> 16);
}

__device__ __forceinline__ float exp2_fast(float x) {
  float r;
  asm("v_exp_f32 %0, %1" : "=v"(r) : "v"(x));
  return r;
}

typedef const __attribute__((address_space(1))) u32 GAS;
typedef __attribute__((address_space(3))) u32 LAS;
__device__ __forceinline__ void g2l16(const u16* g, u16* l) {
  __builtin_amdgcn_global_load_lds((GAS*)g, (LAS*)l, 16, 0, 0);
}

__device__ __forceinline__ f32x16 z16() {
  f32x16 v;
#pragma unroll
  for (int i = 0; i < 16; ++i) v[i] = 0.f;
  return v;
}

// ---------------- conversions (q + 4 weights) + mask scan, one launch ----------------
__global__ void cvt_all(const float* __restrict__ q, u16* __restrict__ qb,
                        const float* __restrict__ w0, u16* __restrict__ o0,
                        const float* __restrict__ w1, u16* __restrict__ o1,
                        const float* __restrict__ w2, u16* __restrict__ o2,
                        const float* __restrict__ w3, u16* __restrict__ o3,
                        const int* __restrict__ mask, int* __restrict__ srcidx,
                        float* __restrict__ madd2c, int* __restrict__ nkv_a,
                        int* __restrict__ nkvp_a, int* __restrict__ nt_a) {
  const int tid = threadIdx.x;
  if (blockIdx.y == 2) {
    if (blockIdx.x >= 2) return;
    const int b = blockIdx.x;
    __shared__ int part[256];
    int loc[8], mv[8];
    int s = 0;
    const int base = b * 2048 + tid * 8;
#pragma unroll
    for (int i = 0; i < 8; ++i) {
      mv[i] = mask[base + i];
      loc[i] = s;
      s += (mv[i] != 0);
    }
    part[tid] = s;
    __syncthreads();
    for (int off = 1; off < 256; off <<= 1) {
      int v = (tid >= off) ? part[tid - off] : 0;
      __syncthreads();
      part[tid] += v;
      __syncthreads();
    }
    const int excl = part[tid] - s;
    const int total = part[255];
#pragma unroll
    for (int i = 0; i < 8; ++i)
      if (mv[i]) srcidx[b * 2048 + excl + loc[i]] = tid * 8 + i;
#pragma unroll
    for (int i = 0; i < 8; ++i) {
      const int j = tid * 8 + i;
      madd2c[b * 2048 + j] = (j < total) ? 0.f : NEGBIG;
    }
    if (tid == 0) {
      const int nkvp = ((total + 63) >> 6) << 6;
      nkv_a[b] = total;
      nkvp_a[b] = nkvp;
      nt_a[b] = nkvp >> 6;
    }
    return;
  }
  const float* s;
  u16* d;
  int i;
  if (blockIdx.y == 0) {
    s = q; d = qb;
    i = blockIdx.x * 256 + tid;
  } else {
    const int wsel = blockIdx.x >> 10;
    s = wsel == 0 ? w0 : wsel == 1 ? w1 : wsel == 2 ? w2 : w3;
    d = wsel == 0 ? o0 : wsel == 1 ? o1 : wsel == 2 ? o2 : o3;
    i = (blockIdx.x & 1023) * 256 + tid;
  }
  f32x4 v = ((const f32x4*)s)[i];
  u16x4 o;
  o[0] = f2bf(v[0]); o[1] = f2bf(v[1]); o[2] = f2bf(v[2]); o[3] = f2bf(v[3]);
  ((u16x4*)d)[i] = o;
}

// gather compacted kv token rows from f32 source, convert to bf16; zero pad rows
__global__ void gather_kv(const float* __restrict__ keyv, const int* __restrict__ srcidx,
                          const int* __restrict__ nkv_a, const int* __restrict__ nkvp_a,
                          u16* __restrict__ kvc) {
  const int j = blockIdx.x;
  const int b = blockIdx.y;
  const int tid = threadIdx.x;
  const int nkv = nkv_a[b];
  if (j < nkv) {
    const int src = srcidx[b * 2048 + j];
    const f32x4 v = *(const f32x4*)&keyv[((size_t)(b * 2048 + src)) * 1024 + tid * 4];
    u16x4 o;
    o[0] = f2bf(v[0]); o[1] = f2bf(v[1]); o[2] = f2bf(v[2]); o[3] = f2bf(v[3]);
    *(u16x4*)&kvc[((size_t)(b * 2048 + j)) * 1024 + tid * 4] = o;
  } else if (j < nkvp_a[b]) {
    u16x4 z = {0, 0, 0, 0};
    *(u16x4*)&kvc[((size_t)(b * 2048 + j)) * 1024 + tid * 4] = z;
  }
}

// ---------------- shared job struct ----------------
struct Jobs {
  const u16* A[3];
  const u16* W[3];
  const float* bias[3];
  void* out[3];
  const int* mlim[3];  // per-batch valid-row count (2048 rows/batch), or null
  int mode[3];
};

// ---------------- GEMM-4wave (m97 shape): QKV. 128x128 tile, acc[4][4]/wave ----------------
__global__ __launch_bounds__(256, 3) void gemm4(Jobs jb) {
  const int z = blockIdx.z;
  const u16* __restrict__ A = jb.A[z];
  const u16* __restrict__ W = jb.W[z];
  const float* __restrict__ bias = jb.bias[z];
  void* __restrict__ out = jb.out[z];
  const int mode = jb.mode[z];
  // bijective XCD swizzle (T1)
  const int lid = blockIdx.y * 8 + blockIdx.x;
  const int sw = (lid & 7) * 32 + (lid >> 3);
  const int m0 = (sw >> 3) * 128, n0 = (sw & 7) * 128;
  const int* mlim = jb.mlim[z];
  if (mlim && ((m0 & 2047) >= mlim[m0 >> 11])) return;

  __shared__ u16 smem[16384];  // As 8192 | Bs 8192 (u16); epilogue reuses as T[128][128]
  u16* As = smem;
  u16* Bs = smem + 8192;
  const int tid = threadIdx.x;
  const int w = tid >> 6, lane = tid & 63;
  const int wr = w >> 1, wc = w & 1;
  const int l15 = lane & 15, l4 = lane >> 4;
  const int srow = lane >> 3, sslot = lane & 7;

  f32x4 acc[4][4];
#pragma unroll
  for (int m = 0; m < 4; ++m)
#pragma unroll
    for (int n = 0; n < 4; ++n) acc[m][n] = (f32x4){0.f, 0.f, 0.f, 0.f};

  for (int k0 = 0; k0 < 1024; k0 += 64) {
    __syncthreads();
#pragma unroll
    for (int it = 0; it < 4; ++it) {
      const int rbase = w * 32 + it * 8;
      const int r = rbase + srow;
      const int ca = ((sslot ^ (r & 7)) << 3);
      g2l16(A + (size_t)(m0 + r) * 1024 + k0 + ca, &As[rbase * 64]);
      g2l16(W + (size_t)(n0 + r) * 1024 + k0 + ca, &Bs[rbase * 64]);
    }
    __syncthreads();

    s16x8 af[4][2], bf[4][2];
#pragma unroll
    for (int m = 0; m < 4; ++m) {
      const int row = wr * 64 + m * 16 + l15;
#pragma unroll
      for (int kk = 0; kk < 2; ++kk) {
        const int slot = (kk * 4 + l4) ^ (row & 7);
        af[m][kk] = *(const s16x8*)&As[row * 64 + slot * 8];
      }
    }
#pragma unroll
    for (int n = 0; n < 4; ++n) {
      const int row = wc * 64 + n * 16 + l15;
#pragma unroll
      for (int kk = 0; kk < 2; ++kk) {
        const int slot = (kk * 4 + l4) ^ (row & 7);
        bf[n][kk] = *(const s16x8*)&Bs[row * 64 + slot * 8];
      }
    }
#pragma unroll
    for (int m = 0; m < 4; ++m)
#pragma unroll
      for (int n = 0; n < 4; ++n)
#pragma unroll
        for (int kk = 0; kk < 2; ++kk)
          acc[m][n] = __builtin_amdgcn_mfma_f32_16x16x32_bf16(af[m][kk], bf[n][kk],
                                                              acc[m][n], 0, 0, 0);
  }

  if (mode != 1) {
#pragma unroll
    for (int n = 0; n < 4; ++n) {
      const int col = n0 + wc * 64 + n * 16 + l15;
      const float bv = bias[col];
#pragma unroll
      for (int m = 0; m < 4; ++m) {
        const int rowb = m0 + wr * 64 + m * 16 + l4 * 4;
#pragma unroll
        for (int j = 0; j < 4; ++j) {
          const float v = acc[m][n][j] + bv;
          if (mode == 2) ((float*)out)[(size_t)(rowb + j) * 1024 + col] = v;
          else           ((u16*)out)[(size_t)(rowb + j) * 1024 + col] = f2bf(v);
        }
      }
    }
  } else {
    __syncthreads();  // all waves done reading As/Bs before reuse as T
    u16* T = smem;    // [128 cols][128 rows], swizzled
#pragma unroll
    for (int n = 0; n < 4; ++n) {
      const int col = wc * 64 + n * 16 + l15;
      const float bv = bias[n0 + col];
#pragma unroll
      for (int m = 0; m < 4; ++m) {
        const int rowb = wr * 64 + m * 16 + l4 * 4;
        u16x4 v;
#pragma unroll
        for (int j = 0; j < 4; ++j) v[j] = f2bf(acc[m][n][j] + bv);
        *(u16x4*)&T[col * 128 + (rowb ^ ((col & 7) * 8))] = v;
      }
    }
    __syncthreads();
    u16* Vt = (u16*)out;
#pragma unroll
    for (int pass = 0; pass < 8; ++pass) {
      const int c = pass * 16 + (tid >> 4);
      const int slot = tid & 15;
      const s16x8 v = *(const s16x8*)&T[c * 128 + ((slot * 8) ^ ((c & 7) * 8))];
      const int cg = n0 + c, h = cg >> 6, d = cg & 63;
      const int rg = m0 + slot * 8, b = rg >> 11, rr = rg & 2047;
      *(s16x8*)&Vt[(((size_t)(b * 16 + h) * 64) + d) * 2048 + rr] = v;
    }
  }
}

// ---------------- GEMM-8wave: O projection ----------------
__global__ __launch_bounds__(512, 4) void gemm8(Jobs jb) {
  const int z = blockIdx.z;
  const u16* __restrict__ A = jb.A[z];
  const u16* __restrict__ W = jb.W[z];
  const float* __restrict__ bias = jb.bias[z];
  void* __restrict__ out = jb.out[z];
  const int mode = jb.mode[z];
  const int lid = blockIdx.y * 8 + blockIdx.x;
  const int sw = (lid & 7) * 32 + (lid >> 3);
  const int m0 = (sw >> 3) * 128, n0 = (sw & 7) * 128;
  const int* mlim = jb.mlim[z];
  if (mlim && ((m0 & 2047) >= mlim[m0 >> 11])) return;

  __shared__ u16 smem[32768];
  const int tid = threadIdx.x;
  const int w = tid >> 6, lane = tid & 63;
  const int wr = w >> 1, wc = w & 1;
  const int l15 = lane & 15, l4 = lane >> 4;
  const int srow = lane >> 3, sslot = lane & 7;

  f32x4 acc[2][4];
#pragma unroll
  for (int m = 0; m < 2; ++m)
#pragma unroll
    for (int n = 0; n < 4; ++n) acc[m][n] = (f32x4){0.f, 0.f, 0.f, 0.f};

  auto STAGE = [&](int buf, int k0) {
    u16* As = smem + buf * 16384;
    u16* Bs = As + 8192;
#pragma unroll
    for (int it = 0; it < 4; ++it) {
      const int rbase = (w & 3) * 32 + it * 8;
      const int r = rbase + srow;
      const int ca = ((sslot ^ (r & 7)) << 3);
      if (w < 4) g2l16(A + (size_t)(m0 + r) * 1024 + k0 + ca, &As[rbase * 64]);
      else       g2l16(W + (size_t)(n0 + r) * 1024 + k0 + ca, &Bs[rbase * 64]);
    }
  };

  STAGE(0, 0);
  __syncthreads();
  int cur = 0;
  for (int k0 = 0; k0 < 1024; k0 += 64) {
    if (k0 < 960) STAGE(cur ^ 1, k0 + 64);
    const u16* As = smem + cur * 16384;
    const u16* Bs = As + 8192;

    s16x8 af[2][2], bf[4][2];
#pragma unroll
    for (int m = 0; m < 2; ++m) {
      const int row = wr * 32 + m * 16 + l15;
#pragma unroll
      for (int kk = 0; kk < 2; ++kk) {
        const int slot = (kk * 4 + l4) ^ (row & 7);
        af[m][kk] = *(const s16x8*)&As[row * 64 + slot * 8];
      }
    }
#pragma unroll
    for (int n = 0; n < 4; ++n) {
      const int row = wc * 64 + n * 16 + l15;
#pragma unroll
      for (int kk = 0; kk < 2; ++kk) {
        const int slot = (kk * 4 + l4) ^ (row & 7);
        bf[n][kk] = *(const s16x8*)&Bs[row * 64 + slot * 8];
      }
    }
#pragma unroll
    for (int m = 0; m < 2; ++m)
#pragma unroll
      for (int n = 0; n < 4; ++n)
#pragma unroll
        for (int kk = 0; kk < 2; ++kk)
          acc[m][n] = __builtin_amdgcn_mfma_f32_16x16x32_bf16(af[m][kk], bf[n][kk],
                                                              acc[m][n], 0, 0, 0);
    __syncthreads();
    cur ^= 1;
  }

#pragma unroll
  for (int n = 0; n < 4; ++n) {
    const int col = n0 + wc * 64 + n * 16 + l15;
    const float bv = bias[col];
#pragma unroll
    for (int m = 0; m < 2; ++m) {
      const int rowb = m0 + wr * 32 + m * 16 + l4 * 4;
#pragma unroll
      for (int j = 0; j < 4; ++j) {
        const float v = acc[m][n][j] + bv;
        if (mode == 2) ((float*)out)[(size_t)(rowb + j) * 1024 + col] = v;
        else           ((u16*)out)[(size_t)(rowb + j) * 1024 + col] = f2bf(v);
      }
    }
  }
}

// ---------------- Flash attention: 4 waves, in-block KV-split, KVBLK=32, dbuf ----------------
// lb folded into smem (LDS exactly 32 KB). launch_bounds (256,4) to keep VGPR=64 (no spill).
__global__ __launch_bounds__(256, 4) void attn_fwd(const u16* __restrict__ Qp,
                                                   const u16* __restrict__ Kp,
                                                   const u16* __restrict__ Vt,
                                                   const float* __restrict__ madd2c,
                                                   const int* __restrict__ nt_a,
                                                   u16* __restrict__ ctx) {
  __shared__ alignas(16) u16 smem[16384];  // [buf][half][ K 32x64 | V 64x32 ]
  // epilogue reuse: Of f32[2][32][64] @ [0,16K); Ot u16 @ [16K,24K); lb @ [24576,25088)
  const int tid = threadIdx.x;
  const int w = tid >> 6, lane = tid & 63;
  const int l31 = lane & 31, h5 = lane >> 5;
  const int qs = w & 1, half = w >> 1;
  const int q0 = blockIdx.x * 64;
  const int head = blockIdx.y, b = blockIdx.z;
  const int srow = lane >> 3, sslot = lane & 7;
  const int vrow = lane >> 2, vslot = lane & 3;
  const int nt = nt_a[b];
  const int kvbase = half * (nt << 5);

  const u16* qbase = Qp + ((size_t)(b * 2048 + q0 + qs * 32 + l31)) * 1024 + head * 64 + h5 * 8;
  s16x8 qf[4];
#pragma unroll
  for (int k = 0; k < 4; ++k) qf[k] = *(const s16x8*)(qbase + k * 16);

  f32x16 oa = z16(), ob = z16();
  float l_run = 0.f;

  auto STAGE = [&](int buf, int t) {
    u16* Ks = &smem[(buf * 2 + half) * 4096];
    u16* Vs = Ks + 2048;
    const int kv0 = kvbase + t * 32;
#pragma unroll
    for (int it = 0; it < 2; ++it) {  // K: 32 rows x 64 cols
      const int rbase = qs * 16 + it * 8;
      const int r = rbase + srow;
      const int ca = ((sslot ^ (r & 7)) << 3);
      g2l16(Kp + (size_t)(b * 2048 + kv0 + r) * 1024 + head * 64 + ca, &Ks[rbase * 64]);
    }
#pragma unroll
    for (int it = 0; it < 2; ++it) {  // V: 64 d-rows x 32 kv-cols
      const int rb = qs * 32 + it * 16;
      const int rv = rb + vrow;
      const int key = (rv & 3) ^ ((rv >> 2) & 3);
      const int cav = ((vslot ^ key) << 3);
      g2l16(Vt + (((size_t)(b * 16 + head) * 64) + rv) * 2048 + kv0 + cav, &Vs[rb * 32]);
    }
  };

  STAGE(0, 0);
  __syncthreads();
  int cur = 0;

  for (int t = 0; t < nt; ++t) {
    if (t < nt - 1) STAGE(cur ^ 1, t + 1);
    const u16* Ks = &smem[(cur * 2 + half) * 4096];
    const u16* Vs = Ks + 2048;

    // S^T = K Q^T. Lane: q=l31; kv=(r&3)+8*(r>>2)+4*h5
    f32x16 s0 = z16();
    __builtin_amdgcn_s_setprio(1);
#pragma unroll
    for (int ks = 0; ks < 4; ++ks) {
      const int cu = (ks * 16 + h5 * 8) ^ ((l31 & 7) * 8);
      const s16x8 kf = *(const s16x8*)&Ks[l31 * 64 + cu];
      s0 = __builtin_amdgcn_mfma_f32_32x32x16_bf16(kf, qf[ks], s0, 0, 0, 0);
    }
    __builtin_amdgcn_s_setprio(0);

    // P = exp2(s*C + mask2), unnormalized. Mask nonzero only on half-1 tail tiles.
    float p[16];
    if (half == 1 && t >= nt - 2) {
      const float* mptr = madd2c + b * 2048 + kvbase + t * 32 + h5 * 4;
      f32x4 mk[4];
#pragma unroll
      for (int c = 0; c < 4; ++c) mk[c] = *(const f32x4*)(mptr + c * 8);
#pragma unroll
      for (int c = 0; c < 4; ++c)
#pragma unroll
        for (int e = 0; e < 4; ++e)
          p[c * 4 + e] = exp2_fast(fmaf(s0[c * 4 + e], C_SCALE, mk[c][e]));
    } else {
#pragma unroll
      for (int i = 0; i < 16; ++i) p[i] = exp2_fast(s0[i] * C_SCALE);
    }

    // row sum: VALU tree + one cross-half exchange
    float t8[8];
#pragma unroll
    for (int i = 0; i < 8; ++i) t8[i] = p[i] + p[i + 8];
#pragma unroll
    for (int i = 0; i < 4; ++i) t8[i] += t8[i + 4];
    float ps = (t8[0] + t8[1]) + (t8[2] + t8[3]);
    ps += __shfl_xor(ps, 32, 64);
    l_run += ps;

    // P -> bf16 B-fragments via cvt_pk + permlane32_swap (T12)
    u32 pk[8];
#pragma unroll
    for (int j = 0; j < 8; ++j) {
      u32 d;
      asm("v_cvt_pk_bf16_f32 %0, %1, %2" : "=v"(d) : "v"(p[2 * j]), "v"(p[2 * j + 1]));
      pk[j] = d;
    }
    s16x8 pf[2];
#pragma unroll
    for (int kk = 0; kk < 2; ++kk) {
      u32 a0 = pk[kk * 4 + 0], a1 = pk[kk * 4 + 1];
      u32 b0 = pk[kk * 4 + 2], b1 = pk[kk * 4 + 3];
      asm("v_permlane32_swap_b32 %0, %1" : "+v"(a0), "+v"(b0));
      asm("v_permlane32_swap_b32 %0, %1" : "+v"(a1), "+v"(b1));
      u32x4 fv; fv[0] = a0; fv[1] = a1; fv[2] = b0; fv[3] = b1;
      pf[kk] = __builtin_bit_cast(s16x8, fv);
    }

    // O^T += V^T P  (A = Vs rows d, k = kv 32)
    const int vkey = (l31 & 3) ^ ((l31 >> 2) & 3);
    __builtin_amdgcn_s_setprio(1);
#pragma unroll
    for (int kk = 0; kk < 2; ++kk) {
      const int c = ((kk * 2 + h5) ^ vkey) << 3;
      const s16x8 vf0 = *(const s16x8*)&Vs[l31 * 32 + c];
      const s16x8 vf1 = *(const s16x8*)&Vs[(32 + l31) * 32 + c];
      oa = __builtin_amdgcn_mfma_f32_32x32x16_bf16(vf0, pf[kk], oa, 0, 0, 0);
      ob = __builtin_amdgcn_mfma_f32_32x32x16_bf16(vf1, pf[kk], ob, 0, 0, 0);
    }
    __builtin_amdgcn_s_setprio(0);

    __syncthreads();
    cur ^= 1;
  }

  // ---- in-block combine of the two KV halves (sum only) ----
  float* lb = (float*)&smem[12288];  // bytes [24576, 25088): f32[4][32]
  lb[w * 32 + l31] = l_run;
  __syncthreads();
  const float l_o = lb[(w ^ 2) * 32 + l31];
  const float inv = 1.f / (l_run + l_o);

  float* Of = (float*)smem;  // [2 qs][32 q][64 d] f32, bytes [0, 16384)
  const int okey = ((l31 & 7) << 3) ^ ((l31 >> 3) << 2);
  if (w >= 2) {
    const int qb2 = (w - 2) * 2048;
#pragma unroll
    for (int dblk = 0; dblk < 2; ++dblk)
#pragma unroll
      for (int g = 0; g < 4; ++g) {
        const int d0 = dblk * 32 + 8 * g + 4 * h5;
        f32x4 v;
#pragma unroll
        for (int e = 0; e < 4; ++e) v[e] = (dblk ? ob[g * 4 + e] : oa[g * 4 + e]);
        *(f32x4*)&Of[qb2 + l31 * 64 + (d0 ^ okey)] = v;
      }
  }
  __syncthreads();
  if (w < 2) {
    u16* Ot = &smem[8192 + qs * 2048];  // bytes [16384, 24576)
#pragma unroll
    for (int dblk = 0; dblk < 2; ++dblk)
#pragma unroll
      for (int g = 0; g < 4; ++g) {
        const int d0 = dblk * 32 + 8 * g + 4 * h5;
        const f32x4 ofv = *(const f32x4*)&Of[qs * 2048 + l31 * 64 + (d0 ^ okey)];
        u16x4 v4;
#pragma unroll
        for (int e = 0; e < 4; ++e) {
          const float fin = ((dblk ? ob[g * 4 + e] : oa[g * 4 + e]) + ofv[e]) * inv;
          v4[e] = f2bf(fin);
        }
        *(u16x4*)&Ot[l31 * 64 + (d0 ^ ((l31 & 7) * 8))] = v4;
      }
#pragma unroll
    for (int pass = 0; pass < 4; ++pass) {
      const int row = pass * 8 + srow;
      const s16x8 v = *(const s16x8*)&Ot[row * 64 + ((sslot * 8) ^ ((row & 7) * 8))];
      *(s16x8*)(ctx + ((size_t)(b * 2048 + q0 + qs * 32 + row)) * 1024 + head * 64 + sslot * 8) = v;
    }
  }
}

extern "C" void kernel_launch(void* const* d_in, const int* in_sizes, int n_in,
                              void* d_out, int out_size, void* d_ws, size_t ws_size,
                              hipStream_t stream) {
  const float* query = (const float*)d_in[0];
  const float* keyv = (const float*)d_in[1];
  const int* mask = (const int*)d_in[2];
  const float* Wq = (const float*)d_in[3];
  const float* bq = (const float*)d_in[4];
  const float* Wk = (const float*)d_in[5];
  const float* bk = (const float*)d_in[6];
  const float* Wv = (const float*)d_in[7];
  const float* bv = (const float*)d_in[8];
  const float* Wo = (const float*)d_in[9];
  const float* bo = (const float*)d_in[10];

  const size_t NTOK = (size_t)4096 * 1024;
  const size_t NW = (size_t)1024 * 1024;
  u16* p = (u16*)d_ws;
  u16* qb = p;  p += NTOK;   // reused as ctx after QKV gemm
  u16* wqb = p; p += NW;
  u16* wkb = p; p += NW;
  u16* wvb = p; p += NW;
  u16* wob = p; p += NW;
  u16* Qp = p;  p += NTOK;
  u16* Kp = p;  p += NTOK;
  u16* Vt = p;  p += NTOK;
  u16* kvc = p; p += NTOK;
  float* madd2c = (float*)p; p += 8192;   // 4096 f32
  int* srcidx = (int*)p; p += 8192;       // 4096 i32
  int* meta = (int*)p;                    // nkv[2], nkvp[2], nt[2]
  int* nkv_a = meta;
  int* nkvp_a = meta + 2;
  int* nt_a = meta + 4;
  u16* ctx = qb;

  cvt_all<<<dim3(4096, 3), 256, 0, stream>>>(query, qb, Wq, wqb, Wk, wkb, Wv, wvb,
                                             Wo, wob, mask, srcidx, madd2c,
                                             nkv_a, nkvp_a, nt_a);
  gather_kv<<<dim3(2048, 2), 256, 0, stream>>>(keyv, srcidx, nkv_a, nkvp_a, kvc);

  Jobs pj;
  pj.A[0] = qb;  pj.W[0] = wqb; pj.bias[0] = bq; pj.out[0] = Qp; pj.mode[0] = 0; pj.mlim[0] = nullptr;
  pj.A[1] = kvc; pj.W[1] = wkb; pj.bias[1] = bk; pj.out[1] = Kp; pj.mode[1] = 0; pj.mlim[1] = nkvp_a;
  pj.A[2] = kvc; pj.W[2] = wvb; pj.bias[2] = bv; pj.out[2] = Vt; pj.mode[2] = 1; pj.mlim[2] = nkvp_a;
  gemm4<<<dim3(8, 32, 3), 256, 0, stream>>>(pj);

  attn_fwd<<<dim3(32, 16, 2), 256, 0, stream>>>(Qp, Kp, Vt, madd2c, nt_a, ctx);

  Jobs oj;
  oj.A[0] = ctx; oj.W[0] = wob; oj.bias[0] = bo; oj.out[0] = d_out; oj.mode[0] = 2; oj.mlim[0] = nullptr;
  oj.A[1] = ctx; oj.W[1] = wob; oj.bias[1] = bo; oj.out[1] = d_out; oj.mode[1] = 2; oj.mlim[1] = nullptr;
  oj.A[2] = ctx; oj.W[2] = wob; oj.bias[2] = bo; oj.out[2] = d_out; oj.mode[2] = 2; oj.mlim[2] = nullptr;
  gemm8<<<dim3(8, 32, 1), 512, 0, stream>>>(oj);
}

// Round 17
// 95.673 us; speedup vs baseline: 1.0286x; 1.0286x over previous
//
#include <hip/hip_runtime.h>

// CrossAttention B=2, L=2048, E=1024, H=16, D=64
// cvt_all(+scan) -> gather+cvt kv -> QKV gemm (4-wave acc[4][4], XCD-swizzled,
// early-exit) -> attn (32x32 swapped MFMA, LDS dbuf, 4-wave KV-split, unnormalized
// softmax, mask loads only on tail tiles) -> O gemm (8-wave, f32 out)
// [r13-proven configuration: best measured 95.75 us]

typedef unsigned short u16;
typedef unsigned int u32;
typedef __attribute__((ext_vector_type(2))) float f32x2;
typedef __attribute__((ext_vector_type(4))) float f32x4;
typedef __attribute__((ext_vector_type(16))) float f32x16;
typedef __attribute__((ext_vector_type(8))) short s16x8;
typedef __attribute__((ext_vector_type(4))) u16 u16x4;
typedef __attribute__((ext_vector_type(4))) u32 u32x4;

#define C_SCALE 0.18033688011112042f  // 0.125 * log2(e)
#define NEGBIG -30000.0f

__device__ __forceinline__ u16 f2bf(float f) {
  u32 u = __builtin_bit_cast(u32, f);
  u += 0x7FFFu + ((u >> 16) & 1u);
  return (u16)(u >> 16);
}

__device__ __forceinline__ float exp2_fast(float x) {
  float r;
  asm("v_exp_f32 %0, %1" : "=v"(r) : "v"(x));
  return r;
}

typedef const __attribute__((address_space(1))) u32 GAS;
typedef __attribute__((address_space(3))) u32 LAS;
__device__ __forceinline__ void g2l16(const u16* g, u16* l) {
  __builtin_amdgcn_global_load_lds((GAS*)g, (LAS*)l, 16, 0, 0);
}

__device__ __forceinline__ f32x16 z16() {
  f32x16 v;
#pragma unroll
  for (int i = 0; i < 16; ++i) v[i] = 0.f;
  return v;
}

// ---------------- conversions (q + 4 weights) + mask scan, one launch ----------------
__global__ void cvt_all(const float* __restrict__ q, u16* __restrict__ qb,
                        const float* __restrict__ w0, u16* __restrict__ o0,
                        const float* __restrict__ w1, u16* __restrict__ o1,
                        const float* __restrict__ w2, u16* __restrict__ o2,
                        const float* __restrict__ w3, u16* __restrict__ o3,
                        const int* __restrict__ mask, int* __restrict__ srcidx,
                        float* __restrict__ madd2c, int* __restrict__ nkv_a,
                        int* __restrict__ nkvp_a, int* __restrict__ nt_a) {
  const int tid = threadIdx.x;
  if (blockIdx.y == 2) {
    // mask scan: 2 working blocks (one per batch)
    if (blockIdx.x >= 2) return;
    const int b = blockIdx.x;
    __shared__ int part[256];
    int loc[8], mv[8];
    int s = 0;
    const int base = b * 2048 + tid * 8;
#pragma unroll
    for (int i = 0; i < 8; ++i) {
      mv[i] = mask[base + i];
      loc[i] = s;
      s += (mv[i] != 0);
    }
    part[tid] = s;
    __syncthreads();
    for (int off = 1; off < 256; off <<= 1) {
      int v = (tid >= off) ? part[tid - off] : 0;
      __syncthreads();
      part[tid] += v;
      __syncthreads();
    }
    const int excl = part[tid] - s;
    const int total = part[255];
#pragma unroll
    for (int i = 0; i < 8; ++i)
      if (mv[i]) srcidx[b * 2048 + excl + loc[i]] = tid * 8 + i;
#pragma unroll
    for (int i = 0; i < 8; ++i) {
      const int j = tid * 8 + i;
      madd2c[b * 2048 + j] = (j < total) ? 0.f : NEGBIG;
    }
    if (tid == 0) {
      const int nkvp = ((total + 63) >> 6) << 6;
      nkv_a[b] = total;
      nkvp_a[b] = nkvp;
      nt_a[b] = nkvp >> 6;
    }
    return;
  }
  const float* s;
  u16* d;
  int i;
  if (blockIdx.y == 0) {
    s = q; d = qb;
    i = blockIdx.x * 256 + tid;
  } else {
    const int wsel = blockIdx.x >> 10;
    s = wsel == 0 ? w0 : wsel == 1 ? w1 : wsel == 2 ? w2 : w3;
    d = wsel == 0 ? o0 : wsel == 1 ? o1 : wsel == 2 ? o2 : o3;
    i = (blockIdx.x & 1023) * 256 + tid;
  }
  f32x4 v = ((const f32x4*)s)[i];
  u16x4 o;
  o[0] = f2bf(v[0]); o[1] = f2bf(v[1]); o[2] = f2bf(v[2]); o[3] = f2bf(v[3]);
  ((u16x4*)d)[i] = o;
}

// gather compacted kv token rows from f32 source, convert to bf16; zero pad rows
__global__ void gather_kv(const float* __restrict__ keyv, const int* __restrict__ srcidx,
                          const int* __restrict__ nkv_a, const int* __restrict__ nkvp_a,
                          u16* __restrict__ kvc) {
  const int j = blockIdx.x;
  const int b = blockIdx.y;
  const int tid = threadIdx.x;
  const int nkv = nkv_a[b];
  if (j < nkv) {
    const int src = srcidx[b * 2048 + j];
    const f32x4 v = *(const f32x4*)&keyv[((size_t)(b * 2048 + src)) * 1024 + tid * 4];
    u16x4 o;
    o[0] = f2bf(v[0]); o[1] = f2bf(v[1]); o[2] = f2bf(v[2]); o[3] = f2bf(v[3]);
    *(u16x4*)&kvc[((size_t)(b * 2048 + j)) * 1024 + tid * 4] = o;
  } else if (j < nkvp_a[b]) {
    u16x4 z = {0, 0, 0, 0};
    *(u16x4*)&kvc[((size_t)(b * 2048 + j)) * 1024 + tid * 4] = z;
  }
}

// ---------------- shared job struct ----------------
struct Jobs {
  const u16* A[3];
  const u16* W[3];
  const float* bias[3];
  void* out[3];
  const int* mlim[3];  // per-batch valid-row count (2048 rows/batch), or null
  int mode[3];
};

// ---------------- GEMM-4wave (m97 shape): QKV. 128x128 tile, acc[4][4]/wave ----------------
__global__ __launch_bounds__(256, 3) void gemm4(Jobs jb) {
  const int z = blockIdx.z;
  const u16* __restrict__ A = jb.A[z];
  const u16* __restrict__ W = jb.W[z];
  const float* __restrict__ bias = jb.bias[z];
  void* __restrict__ out = jb.out[z];
  const int mode = jb.mode[z];
  // bijective XCD swizzle (T1)
  const int lid = blockIdx.y * 8 + blockIdx.x;
  const int sw = (lid & 7) * 32 + (lid >> 3);
  const int m0 = (sw >> 3) * 128, n0 = (sw & 7) * 128;
  const int* mlim = jb.mlim[z];
  if (mlim && ((m0 & 2047) >= mlim[m0 >> 11])) return;

  __shared__ u16 smem[16384];  // As 8192 | Bs 8192 (u16); epilogue reuses as T[128][128]
  u16* As = smem;
  u16* Bs = smem + 8192;
  const int tid = threadIdx.x;
  const int w = tid >> 6, lane = tid & 63;
  const int wr = w >> 1, wc = w & 1;
  const int l15 = lane & 15, l4 = lane >> 4;
  const int srow = lane >> 3, sslot = lane & 7;

  f32x4 acc[4][4];
#pragma unroll
  for (int m = 0; m < 4; ++m)
#pragma unroll
    for (int n = 0; n < 4; ++n) acc[m][n] = (f32x4){0.f, 0.f, 0.f, 0.f};

  for (int k0 = 0; k0 < 1024; k0 += 64) {
    __syncthreads();
#pragma unroll
    for (int it = 0; it < 4; ++it) {
      const int rbase = w * 32 + it * 8;
      const int r = rbase + srow;
      const int ca = ((sslot ^ (r & 7)) << 3);
      g2l16(A + (size_t)(m0 + r) * 1024 + k0 + ca, &As[rbase * 64]);
      g2l16(W + (size_t)(n0 + r) * 1024 + k0 + ca, &Bs[rbase * 64]);
    }
    __syncthreads();

    s16x8 af[4][2], bf[4][2];
#pragma unroll
    for (int m = 0; m < 4; ++m) {
      const int row = wr * 64 + m * 16 + l15;
#pragma unroll
      for (int kk = 0; kk < 2; ++kk) {
        const int slot = (kk * 4 + l4) ^ (row & 7);
        af[m][kk] = *(const s16x8*)&As[row * 64 + slot * 8];
      }
    }
#pragma unroll
    for (int n = 0; n < 4; ++n) {
      const int row = wc * 64 + n * 16 + l15;
#pragma unroll
      for (int kk = 0; kk < 2; ++kk) {
        const int slot = (kk * 4 + l4) ^ (row & 7);
        bf[n][kk] = *(const s16x8*)&Bs[row * 64 + slot * 8];
      }
    }
#pragma unroll
    for (int m = 0; m < 4; ++m)
#pragma unroll
      for (int n = 0; n < 4; ++n)
#pragma unroll
        for (int kk = 0; kk < 2; ++kk)
          acc[m][n] = __builtin_amdgcn_mfma_f32_16x16x32_bf16(af[m][kk], bf[n][kk],
                                                              acc[m][n], 0, 0, 0);
  }

  if (mode != 1) {
#pragma unroll
    for (int n = 0; n < 4; ++n) {
      const int col = n0 + wc * 64 + n * 16 + l15;
      const float bv = bias[col];
#pragma unroll
      for (int m = 0; m < 4; ++m) {
        const int rowb = m0 + wr * 64 + m * 16 + l4 * 4;
#pragma unroll
        for (int j = 0; j < 4; ++j) {
          const float v = acc[m][n][j] + bv;
          if (mode == 2) ((float*)out)[(size_t)(rowb + j) * 1024 + col] = v;
          else           ((u16*)out)[(size_t)(rowb + j) * 1024 + col] = f2bf(v);
        }
      }
    }
  } else {
    __syncthreads();  // all waves done reading As/Bs before reuse as T
    u16* T = smem;    // [128 cols][128 rows], swizzled
#pragma unroll
    for (int n = 0; n < 4; ++n) {
      const int col = wc * 64 + n * 16 + l15;
      const float bv = bias[n0 + col];
#pragma unroll
      for (int m = 0; m < 4; ++m) {
        const int rowb = wr * 64 + m * 16 + l4 * 4;
        u16x4 v;
#pragma unroll
        for (int j = 0; j < 4; ++j) v[j] = f2bf(acc[m][n][j] + bv);
        *(u16x4*)&T[col * 128 + (rowb ^ ((col & 7) * 8))] = v;
      }
    }
    __syncthreads();
    u16* Vt = (u16*)out;
#pragma unroll
    for (int pass = 0; pass < 8; ++pass) {
      const int c = pass * 16 + (tid >> 4);
      const int slot = tid & 15;
      const s16x8 v = *(const s16x8*)&T[c * 128 + ((slot * 8) ^ ((c & 7) * 8))];
      const int cg = n0 + c, h = cg >> 6, d = cg & 63;
      const int rg = m0 + slot * 8, b = rg >> 11, rr = rg & 2047;
      *(s16x8*)&Vt[(((size_t)(b * 16 + h) * 64) + d) * 2048 + rr] = v;
    }
  }
}

// ---------------- GEMM-8wave: O projection ----------------
__global__ __launch_bounds__(512, 4) void gemm8(Jobs jb) {
  const int z = blockIdx.z;
  const u16* __restrict__ A = jb.A[z];
  const u16* __restrict__ W = jb.W[z];
  const float* __restrict__ bias = jb.bias[z];
  void* __restrict__ out = jb.out[z];
  const int mode = jb.mode[z];
  const int lid = blockIdx.y * 8 + blockIdx.x;
  const int sw = (lid & 7) * 32 + (lid >> 3);
  const int m0 = (sw >> 3) * 128, n0 = (sw & 7) * 128;
  const int* mlim = jb.mlim[z];
  if (mlim && ((m0 & 2047) >= mlim[m0 >> 11])) return;

  __shared__ u16 smem[32768];
  const int tid = threadIdx.x;
  const int w = tid >> 6, lane = tid & 63;
  const int wr = w >> 1, wc = w & 1;
  const int l15 = lane & 15, l4 = lane >> 4;
  const int srow = lane >> 3, sslot = lane & 7;

  f32x4 acc[2][4];
#pragma unroll
  for (int m = 0; m < 2; ++m)
#pragma unroll
    for (int n = 0; n < 4; ++n) acc[m][n] = (f32x4){0.f, 0.f, 0.f, 0.f};

  auto STAGE = [&](int buf, int k0) {
    u16* As = smem + buf * 16384;
    u16* Bs = As + 8192;
#pragma unroll
    for (int it = 0; it < 4; ++it) {
      const int rbase = (w & 3) * 32 + it * 8;
      const int r = rbase + srow;
      const int ca = ((sslot ^ (r & 7)) << 3);
      if (w < 4) g2l16(A + (size_t)(m0 + r) * 1024 + k0 + ca, &As[rbase * 64]);
      else       g2l16(W + (size_t)(n0 + r) * 1024 + k0 + ca, &Bs[rbase * 64]);
    }
  };

  STAGE(0, 0);
  __syncthreads();
  int cur = 0;
  for (int k0 = 0; k0 < 1024; k0 += 64) {
    if (k0 < 960) STAGE(cur ^ 1, k0 + 64);
    const u16* As = smem + cur * 16384;
    const u16* Bs = As + 8192;

    s16x8 af[2][2], bf[4][2];
#pragma unroll
    for (int m = 0; m < 2; ++m) {
      const int row = wr * 32 + m * 16 + l15;
#pragma unroll
      for (int kk = 0; kk < 2; ++kk) {
        const int slot = (kk * 4 + l4) ^ (row & 7);
        af[m][kk] = *(const s16x8*)&As[row * 64 + slot * 8];
      }
    }
#pragma unroll
    for (int n = 0; n < 4; ++n) {
      const int row = wc * 64 + n * 16 + l15;
#pragma unroll
      for (int kk = 0; kk < 2; ++kk) {
        const int slot = (kk * 4 + l4) ^ (row & 7);
        bf[n][kk] = *(const s16x8*)&Bs[row * 64 + slot * 8];
      }
    }
#pragma unroll
    for (int m = 0; m < 2; ++m)
#pragma unroll
      for (int n = 0; n < 4; ++n)
#pragma unroll
        for (int kk = 0; kk < 2; ++kk)
          acc[m][n] = __builtin_amdgcn_mfma_f32_16x16x32_bf16(af[m][kk], bf[n][kk],
                                                              acc[m][n], 0, 0, 0);
    __syncthreads();
    cur ^= 1;
  }

#pragma unroll
  for (int n = 0; n < 4; ++n) {
    const int col = n0 + wc * 64 + n * 16 + l15;
    const float bv = bias[col];
#pragma unroll
    for (int m = 0; m < 2; ++m) {
      const int rowb = m0 + wr * 32 + m * 16 + l4 * 4;
#pragma unroll
      for (int j = 0; j < 4; ++j) {
        const float v = acc[m][n][j] + bv;
        if (mode == 2) ((float*)out)[(size_t)(rowb + j) * 1024 + col] = v;
        else           ((u16*)out)[(size_t)(rowb + j) * 1024 + col] = f2bf(v);
      }
    }
  }
}

// ---------------- Flash attention: 4 waves, in-block KV-split, KVBLK=32, dbuf ----------------
// Mask loads only on tail tiles (pads confined to half-1 t>=nt-2); elsewhere u = s*C exactly.
__global__ __launch_bounds__(256, 4) void attn_fwd(const u16* __restrict__ Qp,
                                                   const u16* __restrict__ Kp,
                                                   const u16* __restrict__ Vt,
                                                   const float* __restrict__ madd2c,
                                                   const int* __restrict__ nt_a,
                                                   u16* __restrict__ ctx) {
  __shared__ alignas(16) u16 smem[16384];  // [buf][half][ K 32x64 | V 64x32 ]; reused: Of + Ot
  __shared__ float lb[4][32];
  const int tid = threadIdx.x;
  const int w = tid >> 6, lane = tid & 63;
  const int l31 = lane & 31, h5 = lane >> 5;
  const int qs = w & 1, half = w >> 1;
  const int q0 = blockIdx.x * 64;
  const int head = blockIdx.y, b = blockIdx.z;
  const int srow = lane >> 3, sslot = lane & 7;
  const int vrow = lane >> 2, vslot = lane & 3;
  const int nt = nt_a[b];
  const int kvbase = half * (nt << 5);

  const u16* qbase = Qp + ((size_t)(b * 2048 + q0 + qs * 32 + l31)) * 1024 + head * 64 + h5 * 8;
  s16x8 qf[4];
#pragma unroll
  for (int k = 0; k < 4; ++k) qf[k] = *(const s16x8*)(qbase + k * 16);

  f32x16 oa = z16(), ob = z16();
  float l_run = 0.f;

  auto STAGE = [&](int buf, int t) {
    u16* Ks = &smem[(buf * 2 + half) * 4096];
    u16* Vs = Ks + 2048;
    const int kv0 = kvbase + t * 32;
#pragma unroll
    for (int it = 0; it < 2; ++it) {  // K: 32 rows x 64 cols
      const int rbase = qs * 16 + it * 8;
      const int r = rbase + srow;
      const int ca = ((sslot ^ (r & 7)) << 3);
      g2l16(Kp + (size_t)(b * 2048 + kv0 + r) * 1024 + head * 64 + ca, &Ks[rbase * 64]);
    }
#pragma unroll
    for (int it = 0; it < 2; ++it) {  // V: 64 d-rows x 32 kv-cols
      const int rb = qs * 32 + it * 16;
      const int rv = rb + vrow;
      const int key = (rv & 3) ^ ((rv >> 2) & 3);
      const int cav = ((vslot ^ key) << 3);
      g2l16(Vt + (((size_t)(b * 16 + head) * 64) + rv) * 2048 + kv0 + cav, &Vs[rb * 32]);
    }
  };

  STAGE(0, 0);
  __syncthreads();
  int cur = 0;

  for (int t = 0; t < nt; ++t) {
    if (t < nt - 1) STAGE(cur ^ 1, t + 1);
    const u16* Ks = &smem[(cur * 2 + half) * 4096];
    const u16* Vs = Ks + 2048;

    // S^T = K Q^T. Lane: q=l31; kv=(r&3)+8*(r>>2)+4*h5
    f32x16 s0 = z16();
    __builtin_amdgcn_s_setprio(1);
#pragma unroll
    for (int ks = 0; ks < 4; ++ks) {
      const int cu = (ks * 16 + h5 * 8) ^ ((l31 & 7) * 8);
      const s16x8 kf = *(const s16x8*)&Ks[l31 * 64 + cu];
      s0 = __builtin_amdgcn_mfma_f32_32x32x16_bf16(kf, qf[ks], s0, 0, 0, 0);
    }
    __builtin_amdgcn_s_setprio(0);

    // P = exp2(s*C + mask2), unnormalized. Mask nonzero only on half-1 tail tiles.
    float p[16];
    if (half == 1 && t >= nt - 2) {
      const float* mptr = madd2c + b * 2048 + kvbase + t * 32 + h5 * 4;
      f32x4 mk[4];
#pragma unroll
      for (int c = 0; c < 4; ++c) mk[c] = *(const f32x4*)(mptr + c * 8);
#pragma unroll
      for (int c = 0; c < 4; ++c)
#pragma unroll
        for (int e = 0; e < 4; ++e)
          p[c * 4 + e] = exp2_fast(fmaf(s0[c * 4 + e], C_SCALE, mk[c][e]));
    } else {
#pragma unroll
      for (int i = 0; i < 16; ++i) p[i] = exp2_fast(s0[i] * C_SCALE);
    }

    // row sum: VALU tree + one cross-half exchange
    float t8[8];
#pragma unroll
    for (int i = 0; i < 8; ++i) t8[i] = p[i] + p[i + 8];
#pragma unroll
    for (int i = 0; i < 4; ++i) t8[i] += t8[i + 4];
    float ps = (t8[0] + t8[1]) + (t8[2] + t8[3]);
    ps += __shfl_xor(ps, 32, 64);
    l_run += ps;

    // P -> bf16 B-fragments via cvt_pk + permlane32_swap (T12)
    u32 pk[8];
#pragma unroll
    for (int j = 0; j < 8; ++j) {
      u32 d;
      asm("v_cvt_pk_bf16_f32 %0, %1, %2" : "=v"(d) : "v"(p[2 * j]), "v"(p[2 * j + 1]));
      pk[j] = d;
    }
    s16x8 pf[2];
#pragma unroll
    for (int kk = 0; kk < 2; ++kk) {
      u32 a0 = pk[kk * 4 + 0], a1 = pk[kk * 4 + 1];
      u32 b0 = pk[kk * 4 + 2], b1 = pk[kk * 4 + 3];
      asm("v_permlane32_swap_b32 %0, %1" : "+v"(a0), "+v"(b0));
      asm("v_permlane32_swap_b32 %0, %1" : "+v"(a1), "+v"(b1));
      u32x4 fv; fv[0] = a0; fv[1] = a1; fv[2] = b0; fv[3] = b1;
      pf[kk] = __builtin_bit_cast(s16x8, fv);
    }

    // O^T += V^T P  (A = Vs rows d, k = kv 32)
    const int vkey = (l31 & 3) ^ ((l31 >> 2) & 3);
    __builtin_amdgcn_s_setprio(1);
#pragma unroll
    for (int kk = 0; kk < 2; ++kk) {
      const int c = ((kk * 2 + h5) ^ vkey) << 3;
      const s16x8 vf0 = *(const s16x8*)&Vs[l31 * 32 + c];
      const s16x8 vf1 = *(const s16x8*)&Vs[(32 + l31) * 32 + c];
      oa = __builtin_amdgcn_mfma_f32_32x32x16_bf16(vf0, pf[kk], oa, 0, 0, 0);
      ob = __builtin_amdgcn_mfma_f32_32x32x16_bf16(vf1, pf[kk], ob, 0, 0, 0);
    }
    __builtin_amdgcn_s_setprio(0);

    __syncthreads();
    cur ^= 1;
  }

  // ---- in-block combine of the two KV halves (sum only) ----
  lb[w][l31] = l_run;
  __syncthreads();
  const float l_o = lb[w ^ 2][l31];
  const float inv = 1.f / (l_run + l_o);

  float* Of = (float*)smem;  // [2 qs][32 q][64 d], f32, swizzled
  const int okey = ((l31 & 7) << 3) ^ ((l31 >> 3) << 2);
  if (w >= 2) {
    const int qb2 = (w - 2) * 2048;
#pragma unroll
    for (int dblk = 0; dblk < 2; ++dblk)
#pragma unroll
      for (int g = 0; g < 4; ++g) {
        const int d0 = dblk * 32 + 8 * g + 4 * h5;
        f32x4 v;
#pragma unroll
        for (int e = 0; e < 4; ++e) v[e] = (dblk ? ob[g * 4 + e] : oa[g * 4 + e]);
        *(f32x4*)&Of[qb2 + l31 * 64 + (d0 ^ okey)] = v;
      }
  }
  __syncthreads();
  if (w < 2) {
    u16* Ot = &smem[8192 + qs * 2048];
#pragma unroll
    for (int dblk = 0; dblk < 2; ++dblk)
#pragma unroll
      for (int g = 0; g < 4; ++g) {
        const int d0 = dblk * 32 + 8 * g + 4 * h5;
        const f32x4 ofv = *(const f32x4*)&Of[qs * 2048 + l31 * 64 + (d0 ^ okey)];
        u16x4 v4;
#pragma unroll
        for (int e = 0; e < 4; ++e) {
          const float fin = ((dblk ? ob[g * 4 + e] : oa[g * 4 + e]) + ofv[e]) * inv;
          v4[e] = f2bf(fin);
        }
        *(u16x4*)&Ot[l31 * 64 + (d0 ^ ((l31 & 7) * 8))] = v4;
      }
#pragma unroll
    for (int pass = 0; pass < 4; ++pass) {
      const int row = pass * 8 + srow;
      const s16x8 v = *(const s16x8*)&Ot[row * 64 + ((sslot * 8) ^ ((row & 7) * 8))];
      *(s16x8*)(ctx + ((size_t)(b * 2048 + q0 + qs * 32 + row)) * 1024 + head * 64 + sslot * 8) = v;
    }
  }
}

extern "C" void kernel_launch(void* const* d_in, const int* in_sizes, int n_in,
                              void* d_out, int out_size, void* d_ws, size_t ws_size,
                              hipStream_t stream) {
  const float* query = (const float*)d_in[0];
  const float* keyv = (const float*)d_in[1];
  const int* mask = (const int*)d_in[2];
  const float* Wq = (const float*)d_in[3];
  const float* bq = (const float*)d_in[4];
  const float* Wk = (const float*)d_in[5];
  const float* bk = (const float*)d_in[6];
  const float* Wv = (const float*)d_in[7];
  const float* bv = (const float*)d_in[8];
  const float* Wo = (const float*)d_in[9];
  const float* bo = (const float*)d_in[10];

  const size_t NTOK = (size_t)4096 * 1024;
  const size_t NW = (size_t)1024 * 1024;
  u16* p = (u16*)d_ws;
  u16* qb = p;  p += NTOK;   // reused as ctx after QKV gemm
  u16* wqb = p; p += NW;
  u16* wkb = p; p += NW;
  u16* wvb = p; p += NW;
  u16* wob = p; p += NW;
  u16* Qp = p;  p += NTOK;
  u16* Kp = p;  p += NTOK;
  u16* Vt = p;  p += NTOK;
  u16* kvc = p; p += NTOK;
  float* madd2c = (float*)p; p += 8192;   // 4096 f32
  int* srcidx = (int*)p; p += 8192;       // 4096 i32
  int* meta = (int*)p;                    // nkv[2], nkvp[2], nt[2]
  int* nkv_a = meta;
  int* nkvp_a = meta + 2;
  int* nt_a = meta + 4;
  u16* ctx = qb;

  cvt_all<<<dim3(4096, 3), 256, 0, stream>>>(query, qb, Wq, wqb, Wk, wkb, Wv, wvb,
                                             Wo, wob, mask, srcidx, madd2c,
                                             nkv_a, nkvp_a, nt_a);
  gather_kv<<<dim3(2048, 2), 256, 0, stream>>>(keyv, srcidx, nkv_a, nkvp_a, kvc);

  Jobs pj;
  pj.A[0] = qb;  pj.W[0] = wqb; pj.bias[0] = bq; pj.out[0] = Qp; pj.mode[0] = 0; pj.mlim[0] = nullptr;
  pj.A[1] = kvc; pj.W[1] = wkb; pj.bias[1] = bk; pj.out[1] = Kp; pj.mode[1] = 0; pj.mlim[1] = nkvp_a;
  pj.A[2] = kvc; pj.W[2] = wvb; pj.bias[2] = bv; pj.out[2] = Vt; pj.mode[2] = 1; pj.mlim[2] = nkvp_a;
  gemm4<<<dim3(8, 32, 3), 256, 0, stream>>>(pj);

  attn_fwd<<<dim3(32, 16, 2), 256, 0, stream>>>(Qp, Kp, Vt, madd2c, nt_a, ctx);

  Jobs oj;
  oj.A[0] = ctx; oj.W[0] = wob; oj.bias[0] = bo; oj.out[0] = d_out; oj.mode[0] = 2; oj.mlim[0] = nullptr;
  oj.A[1] = ctx; oj.W[1] = wob; oj.bias[1] = bo; oj.out[1] = d_out; oj.mode[1] = 2; oj.mlim[1] = nullptr;
  oj.A[2] = ctx; oj.W[2] = wob; oj.bias[2] = bo; oj.out[2] = d_out; oj.mode[2] = 2; oj.mlim[2] = nullptr;
  gemm8<<<dim3(8, 32, 1), 512, 0, stream>>>(oj);
}